// Round 6
// baseline (1001.600 us; speedup 1.0000x reference)
//
#include <hip/hip_runtime.h>

// Fused SIREN INR round 12. r10 base (724us best: TOK=128, 512 thr,
// 16x16x32 MFMA, fragment-ordered weights, chunk-major LDS, rolling a[3],
// b double-buffer, no-fract hw sine, 2 barriers/layer) + two cuts to the
// serial epilogue / layer-entry path:
//  (1) bias folded into MFMA acc INIT (C-in = bias) + W pre-scaled by
//      C_SC at convert: epilogue = sin(acc)+cvt, fmaf deleted.
//  (2) cross-layer a[0],a[1]+bias prefetch issued at the WAR barrier,
//      under the epilogue VALU: L2 link is idle there; kills the
//      ~300-500cyc layer-entry operand stall.
// LEDGER (locked):
//  - Per-CU L2 weight stream = 47MB = ~352us floor; MFMA busy ~363us.
//    K-loop co-saturates BOTH -> no slack to hide epilogue; any 2x
//    weight traffic hits the L2 wall (r7 787us, r9 918us).
//  - Registers: acc 128 AGPR + ~128 VGPR = 256 = 2-wave cap. No dual
//    acc -> no deferred epilogue.
//  - Intra-block desync (r11 flags): neutral; WAR barrier re-syncs
//    every layer. Epilogue VALU (~200us) is structurally serial.
//  - fract-drop safe (r10, -23us VALU). 32x32x16 neutral (r8).
//  - Composite floor ~ max(MFMA 363, L2 352) + VALU 200 ~ 570us + slop.

#define L_TOTAL 262144
#define TOK 128
#define THREADS 512
#define C_SC 4.77464829275686f  // 30/(2*pi)

typedef _Float16 f16x8 __attribute__((ext_vector_type(8)));
typedef _Float16 f16x4 __attribute__((ext_vector_type(4)));
typedef float    f32x4 __attribute__((ext_vector_type(4)));

#define N1 (512 * 256)                 // W_first elems
#define N2 (N1 + 5 * 512 * 512)        // + W_hidden
#define N3 (N2 + 16 * 512)             // + W_out padded to 16 rows
#define NBIAS 3072                     // 512 first + 5*512 hidden (pre-scaled)

// Fragment-ordered destination for first+hidden weights (PRE-SCALED by
// C_SC so the MFMA output is already in revolutions):
// dst[((mt*KS + ks)*64 + lane)*8 + e] = C_SC * W[row=mt*16+(lane&15)]
//                                              [col=ks*32+(lane>>4)*8+e]
// Out layer kept UNSCALED (no sine after it).
__global__ void convert_weights(const float* __restrict__ Wf,
                                const float* __restrict__ Wh,
                                const float* __restrict__ Wo,
                                const float* __restrict__ bf,
                                const float* __restrict__ bh,
                                _Float16* __restrict__ o,
                                float* __restrict__ biasC) {
  int i = blockIdx.x * blockDim.x + threadIdx.x;
  if (i < N3) {
    float v;
    if (i < N1) {                      // first layer: 512x256, KS=8
      const int blk = i >> 9, w = i & 511;
      const int lane = w >> 3, e = w & 7;
      const int mt = blk >> 3, ks = blk & 7;
      const int row = mt * 16 + (lane & 15);
      const int col = ks * 32 + (lane >> 4) * 8 + e;
      v = Wf[row * 256 + col] * C_SC;
    } else if (i < N2) {               // hidden: 5 x 512x512, KS=16
      int j = i - N1;
      const int l = j >> 18;
      j &= (1 << 18) - 1;
      const int blk = j >> 9, w = j & 511;
      const int lane = w >> 3, e = w & 7;
      const int mt = blk >> 4, ks = blk & 15;
      const int row = mt * 16 + (lane & 15);
      const int col = ks * 32 + (lane >> 4) * 8 + e;
      v = Wh[l * (512 * 512) + row * 512 + col] * C_SC;
    } else {                           // out layer: row-major, padded 16x512
      const int r = (i - N2) >> 9, c = (i - N2) & 511;
      v = (r < 3) ? Wo[r * 512 + c] : 0.0f;
    }
    o[i] = (_Float16)v;
  } else if (i < N3 + NBIAS) {
    int j = i - N3;
    biasC[j] = (j < 512 ? bf[j] : bh[j - 512]) * C_SC;
  }
}

// h LDS layout: elem addr = (chunk*128 + token)*8 + (f&7), chunk = f>>3.
// b-frag ds_read_b128 addr16B = chunk*128 + token: linear in lane ->
// conflict-free.
__device__ __forceinline__ int h_elem(int chunk, int token) {
  return (chunk * 128 + token) * 8;
}

// One sine layer: h <- sin(Wc h + bc) (Wc,bc pre-scaled to revolutions).
// M=512 (8 waves x 64 feats), N=128 tokens (8 ntiles), K templated.
// On entry: a[0],a[1] and bb hold THIS layer's first two a-frag groups
// and bias (prefetched by the previous layer / prologue). If KN>0, this
// layer prefetches the next layer's a[0],a[1],bb under its epilogue.
template <int K, int KN>
__device__ __forceinline__ void sine_layer(
    const _Float16* __restrict__ W, const _Float16* __restrict__ Wnext,
    const float* __restrict__ biasNext, _Float16* hb, f16x8 (&a)[3][4],
    f32x4 (&bb)[4], int lane, int lr, int lg, int m0) {
  constexpr int KS = K / 32;
  f32x4 acc[4][8];
#pragma unroll
  for (int mt = 0; mt < 4; ++mt)
#pragma unroll
    for (int nt = 0; nt < 8; ++nt)
      acc[mt][nt] = bb[mt];  // bias folded into MFMA C-in

  // per-mt fragment-ordered base: one contiguous 1KB burst per (mt, ks)
  const _Float16* wb[4];
#pragma unroll
  for (int mt = 0; mt < 4; ++mt)
    wb[mt] = &W[(((m0 >> 4) + mt) * KS) * 512 + lane * 8];

  f16x8 b[2][8];
#pragma unroll
  for (int nt = 0; nt < 8; ++nt)
    b[0][nt] = *(const f16x8*)&hb[h_elem(lg, nt * 16 + lr)];

#pragma unroll
  for (int ks = 0; ks < KS; ++ks) {
    const int cur = ks & 1;
    const int ai = ks % 3;
    if (ks + 1 < KS) {  // prefetch next k-step's b-frags under these MFMAs
#pragma unroll
      for (int nt = 0; nt < 8; ++nt)
        b[cur ^ 1][nt] =
            *(const f16x8*)&hb[h_elem((ks + 1) * 4 + lg, nt * 16 + lr)];
    }
    if (ks + 2 < KS) {  // 2-deep a-prefetch (~320cyc cover)
#pragma unroll
      for (int mt = 0; mt < 4; ++mt)
        a[(ks + 2) % 3][mt] = *(const f16x8*)(wb[mt] + (ks + 2) * 512);
    }
#pragma unroll
    for (int mt = 0; mt < 4; ++mt)
#pragma unroll
      for (int nt = 0; nt < 8; ++nt)
        acc[mt][nt] = __builtin_amdgcn_mfma_f32_16x16x32_f16(
            a[ai][mt], b[cur][nt], acc[mt][nt], 0, 0, 0);
  }
  __syncthreads();  // WAR: all reads of old h done before overwrite

  if constexpr (KN > 0) {  // next layer's operands, issued under epilogue
#pragma unroll
    for (int mt = 0; mt < 4; ++mt) {
      const _Float16* p = &Wnext[(((m0 >> 4) + mt) * KN) * 512 + lane * 8];
      a[0][mt] = *(const f16x8*)p;
      a[1][mt] = *(const f16x8*)(p + 512);
      bb[mt] = *(const f32x4*)&biasNext[m0 + mt * 16 + lg * 4];
    }
  }

#pragma unroll
  for (int mt = 0; mt < 4; ++mt) {
    const int ob = m0 + mt * 16 + lg * 4;  // 4 consecutive out-features
    const int wbase = (ob >> 3) * 128 * 8 + (ob & 7);
#pragma unroll
    for (int nt = 0; nt < 8; ++nt) {
      f16x4 hv;
#pragma unroll
      for (int r = 0; r < 4; ++r) {
        // acc already = revolutions (scaled W + bias in C-init);
        // |acc| <= ~9.1 << 256: hw v_sin reduces internally
        hv[r] = (_Float16)__builtin_amdgcn_sinf(acc[mt][nt][r]);
      }
      *(f16x4*)&hb[wbase + (nt * 16 + lr) * 8] = hv;
    }
  }
  __syncthreads();
}

__global__ __launch_bounds__(THREADS, 2) void siren_kernel(
    const float* __restrict__ coords, const float* __restrict__ bff,
    const float* __restrict__ biasC, const float* __restrict__ b_out,
    const _Float16* __restrict__ wf, const _Float16* __restrict__ wh,
    const _Float16* __restrict__ wo, float* __restrict__ out) {
  extern __shared__ _Float16 hb[];  // chunk-major: [64 chunks][128 tok][8]
  const int tid = threadIdx.x;
  const int t0 = blockIdx.x * TOK;

  // Break 2-wave/SIMD lockstep (kept from r10's best config).
  if ((tid >> 6) < 4) __builtin_amdgcn_s_setprio(1);

  const int lane = tid & 63;
  const int lr = lane & 15;   // A: weight row / B: token / C: token col
  const int lg = lane >> 4;   // k-group for frags, row-group for C
  const int wave = tid >> 6;
  const int m0 = wave * 64;   // wave's 64-feature output slice

  // First layer's a[0],a[1]+bias issued BEFORE FF: latency hides under it.
  f16x8 a[3][4];
  f32x4 bb[4];
#pragma unroll
  for (int mt = 0; mt < 4; ++mt) {
    const _Float16* p = &wf[(((m0 >> 4) + mt) * 8) * 512 + lane * 8];
    a[0][mt] = *(const f16x8*)p;
    a[1][mt] = *(const f16x8*)(p + 512);
    bb[mt] = *(const f32x4*)&biasC[m0 + mt * 16 + lg * 4];
  }

  // ---- Fourier features: chunks q*4+cb (sin), 16+q*4+cb (cos) ----
  {
    const int t = tid & 127;   // token (wave = 64 consecutive tokens)
    const int q = tid >> 7;    // feature octant: proj j in [q*32, q*32+32)
    const float c0 = coords[(t0 + t) * 3 + 0];
    const float c1 = coords[(t0 + t) * 3 + 1];
    const float c2 = coords[(t0 + t) * 3 + 2];
#pragma unroll
    for (int cb = 0; cb < 4; ++cb) {
      f16x8 sv, cv;
#pragma unroll
      for (int e = 0; e < 8; ++e) {
        const int j = q * 32 + cb * 8 + e;
        // r in revolutions, |r| <= 3*max|B_ff| ~ 114 << 256: no fract
        float r = fmaf(c0, bff[j], fmaf(c1, bff[128 + j], c2 * bff[256 + j]));
        sv[e] = (_Float16)__builtin_amdgcn_sinf(r);
        cv[e] = (_Float16)__builtin_amdgcn_cosf(r);
      }
      *(f16x8*)&hb[h_elem(q * 4 + cb, t)] = sv;        // lane-linear store
      *(f16x8*)&hb[h_elem(16 + q * 4 + cb, t)] = cv;
    }
  }
  __syncthreads();

  sine_layer<256, 16>(wf, wh, biasC + 512, hb, a, bb, lane, lr, lg, m0);
#pragma unroll 1
  for (int l = 0; l < 4; ++l)
    sine_layer<512, 16>(wh + l * (512 * 512), wh + (l + 1) * (512 * 512),
                        biasC + 512 + (l + 1) * 512, hb, a, bb, lane, lr, lg,
                        m0);
  sine_layer<512, 0>(wh + 4 * (512 * 512), nullptr, nullptr, hb, a, bb, lane,
                     lr, lg, m0);

  // ---- final linear: out[t][0..2], 16 tokens per wave, 8 waves ----
  {
    f32x4 acc = {0.f, 0.f, 0.f, 0.f};
#pragma unroll
    for (int ks = 0; ks < 16; ++ks) {
      f16x8 av = *(const f16x8*)&wo[lr * 512 + ks * 32 + lg * 8];
      f16x8 bv = *(const f16x8*)&hb[h_elem(ks * 4 + lg, wave * 16 + lr)];
      acc = __builtin_amdgcn_mfma_f32_16x16x32_f16(av, bv, acc, 0, 0, 0);
    }
    if (lg == 0) {  // C rows 0..3 in lanes 0..15; out-feature = reg idx
      const int t = t0 + wave * 16 + lr;
      out[t * 3 + 0] = acc[0] + b_out[0];
      out[t * 3 + 1] = acc[1] + b_out[1];
      out[t * 3 + 2] = acc[2] + b_out[2];
    }
  }
}

extern "C" void kernel_launch(void* const* d_in, const int* in_sizes, int n_in,
                              void* d_out, int out_size, void* d_ws,
                              size_t ws_size, hipStream_t stream) {
  const float* coords = (const float*)d_in[0];
  const float* bff    = (const float*)d_in[1];
  const float* Wf     = (const float*)d_in[2];
  const float* bf     = (const float*)d_in[3];
  const float* Wh     = (const float*)d_in[4];
  const float* bh     = (const float*)d_in[5];
  const float* Wo     = (const float*)d_in[6];
  const float* bo     = (const float*)d_in[7];
  float* out = (float*)d_out;

  _Float16* w16 = (_Float16*)d_ws;
  float* biasC = (float*)(w16 + N3);  // 16B-aligned (N3*2 % 16 == 0)

  convert_weights<<<(N3 + NBIAS + 255) / 256, 256, 0, stream>>>(
      Wf, Wh, Wo, bf, bh, w16, biasC);

  const size_t lds_bytes = 64 * 128 * 8 * sizeof(_Float16);  // 131072
  siren_kernel<<<L_TOTAL / TOK, THREADS, lds_bytes, stream>>>(
      coords, bff, biasC, bo, w16, w16 + N1, w16 + N2, out);
}

// Round 7
// 701.378 us; speedup vs baseline: 1.4280x; 1.4280x over previous
//
#include <hip/hip_runtime.h>

// Fused SIREN INR round 13. r10 base (724us best: TOK=128, 512 thr,
// 16x16x32 MFMA, fragment-ordered weights, chunk-major LDS, rolling a[3],
// b double-buffer, no-fract hw sine, 2 barriers/layer, setprio split) +
// BIAS-FOLD ONLY: W pre-scaled by C_SC at convert (numerics validated in
// r12: absmax unchanged), bias loaded at layer ENTRY (dead before the
// epilogue -> no extra live state), acc init = bias as MFMA C-in.
// Epilogue per element: v_sin + cvt (fmaf deleted from the serial path).
// LEDGER (locked):
//  - ZERO extra live regs across the epilogue: r12's cross-layer a/bb
//    carry (64 VGPR) spilled to scratch (FETCH 16->280GB, WRITE 30->394GB,
//    724->999us). r11's flag state did the same (its FETCH/WRITE anomaly).
//  - Per-CU L2 weight stream = 47MB = ~352us floor; MFMA busy ~363us.
//    K-loop co-saturates BOTH -> 2x weight traffic is fatal (r7 787,
//    r9 918). Kills token-split, MT=4, TOK=64/2-block.
//  - Registers: acc 128 AGPR + ~128 VGPR = 256 = 2-wave cap. No dual acc.
//  - Intra-block desync (r11): neutral; WAR barrier re-syncs each layer.
//  - fract-drop safe (r10, -23us). 32x32x16 neutral (r8).
//  - Composite floor ~ max(MFMA 363, L2 352) + serial VALU ~190 ~ 560us.

#define L_TOTAL 262144
#define TOK 128
#define THREADS 512
#define C_SC 4.77464829275686f  // 30/(2*pi)

typedef _Float16 f16x8 __attribute__((ext_vector_type(8)));
typedef _Float16 f16x4 __attribute__((ext_vector_type(4)));
typedef float    f32x4 __attribute__((ext_vector_type(4)));

#define N1 (512 * 256)                 // W_first elems
#define N2 (N1 + 5 * 512 * 512)        // + W_hidden
#define N3 (N2 + 16 * 512)             // + W_out padded to 16 rows
#define NBIAS 3072                     // 512 first + 5*512 hidden (pre-scaled)

// Fragment-ordered destination for first+hidden weights, PRE-SCALED by
// C_SC (MFMA output is then already in revolutions):
// dst[((mt*KS + ks)*64 + lane)*8 + e] = C_SC * W[row=mt*16+(lane&15)]
//                                              [col=ks*32+(lane>>4)*8+e]
// Out layer kept UNSCALED (no sine after it).
__global__ void convert_weights(const float* __restrict__ Wf,
                                const float* __restrict__ Wh,
                                const float* __restrict__ Wo,
                                const float* __restrict__ bf,
                                const float* __restrict__ bh,
                                _Float16* __restrict__ o,
                                float* __restrict__ biasC) {
  int i = blockIdx.x * blockDim.x + threadIdx.x;
  if (i < N3) {
    float v;
    if (i < N1) {                      // first layer: 512x256, KS=8
      const int blk = i >> 9, w = i & 511;
      const int lane = w >> 3, e = w & 7;
      const int mt = blk >> 3, ks = blk & 7;
      const int row = mt * 16 + (lane & 15);
      const int col = ks * 32 + (lane >> 4) * 8 + e;
      v = Wf[row * 256 + col] * C_SC;
    } else if (i < N2) {               // hidden: 5 x 512x512, KS=16
      int j = i - N1;
      const int l = j >> 18;
      j &= (1 << 18) - 1;
      const int blk = j >> 9, w = j & 511;
      const int lane = w >> 3, e = w & 7;
      const int mt = blk >> 4, ks = blk & 15;
      const int row = mt * 16 + (lane & 15);
      const int col = ks * 32 + (lane >> 4) * 8 + e;
      v = Wh[l * (512 * 512) + row * 512 + col] * C_SC;
    } else {                           // out layer: row-major, padded 16x512
      const int r = (i - N2) >> 9, c = (i - N2) & 511;
      v = (r < 3) ? Wo[r * 512 + c] : 0.0f;
    }
    o[i] = (_Float16)v;
  } else if (i < N3 + NBIAS) {
    int j = i - N3;
    biasC[j] = (j < 512 ? bf[j] : bh[j - 512]) * C_SC;
  }
}

// h LDS layout: elem addr = (chunk*128 + token)*8 + (f&7), chunk = f>>3.
// b-frag ds_read_b128 addr16B = chunk*128 + token: linear in lane ->
// conflict-free.
__device__ __forceinline__ int h_elem(int chunk, int token) {
  return (chunk * 128 + token) * 8;
}

// One sine layer: h <- sin(Wc h + bc) (Wc,bc pre-scaled to revolutions).
// M=512 (8 waves x 64 feats), N=128 tokens (8 ntiles), K templated.
// Bias is loaded HERE and folded into the MFMA C-init; it is dead before
// the K-loop ends -> no extra live state across the epilogue.
template <int K>
__device__ __forceinline__ void sine_layer(const _Float16* __restrict__ W,
                                           const float* __restrict__ biasC,
                                           _Float16* hb, int lane, int lr,
                                           int lg, int m0) {
  constexpr int KS = K / 32;

  f32x4 acc[4][8];
#pragma unroll
  for (int mt = 0; mt < 4; ++mt) {
    const f32x4 bb = *(const f32x4*)&biasC[m0 + mt * 16 + lg * 4];
#pragma unroll
    for (int nt = 0; nt < 8; ++nt)
      acc[mt][nt] = bb;  // bias folded into MFMA C-in
  }

  // per-mt fragment-ordered base: one contiguous 1KB burst per (mt, ks)
  const _Float16* wb[4];
#pragma unroll
  for (int mt = 0; mt < 4; ++mt)
    wb[mt] = &W[(((m0 >> 4) + mt) * KS) * 512 + lane * 8];

  f16x8 a[3][4], b[2][8];
#pragma unroll
  for (int mt = 0; mt < 4; ++mt) a[0][mt] = *(const f16x8*)(wb[mt]);
#pragma unroll
  for (int mt = 0; mt < 4; ++mt) a[1][mt] = *(const f16x8*)(wb[mt] + 512);
#pragma unroll
  for (int nt = 0; nt < 8; ++nt)
    b[0][nt] = *(const f16x8*)&hb[h_elem(lg, nt * 16 + lr)];

#pragma unroll
  for (int ks = 0; ks < KS; ++ks) {
    const int cur = ks & 1;
    const int ai = ks % 3;
    if (ks + 1 < KS) {  // prefetch next k-step's b-frags under these MFMAs
#pragma unroll
      for (int nt = 0; nt < 8; ++nt)
        b[cur ^ 1][nt] =
            *(const f16x8*)&hb[h_elem((ks + 1) * 4 + lg, nt * 16 + lr)];
    }
    if (ks + 2 < KS) {  // 2-deep a-prefetch (~320cyc cover)
#pragma unroll
      for (int mt = 0; mt < 4; ++mt)
        a[(ks + 2) % 3][mt] = *(const f16x8*)(wb[mt] + (ks + 2) * 512);
    }
#pragma unroll
    for (int mt = 0; mt < 4; ++mt)
#pragma unroll
      for (int nt = 0; nt < 8; ++nt)
        acc[mt][nt] = __builtin_amdgcn_mfma_f32_16x16x32_f16(
            a[ai][mt], b[cur][nt], acc[mt][nt], 0, 0, 0);
  }
  __syncthreads();  // WAR: all reads of old h done before overwrite

#pragma unroll
  for (int mt = 0; mt < 4; ++mt) {
    const int ob = m0 + mt * 16 + lg * 4;  // 4 consecutive out-features
    const int wbase = (ob >> 3) * 128 * 8 + (ob & 7);
#pragma unroll
    for (int nt = 0; nt < 8; ++nt) {
      f16x4 hv;
#pragma unroll
      for (int r = 0; r < 4; ++r) {
        // acc already = revolutions (pre-scaled W + bias C-init);
        // |acc| <= ~9.1 << 256: hw v_sin reduces internally
        hv[r] = (_Float16)__builtin_amdgcn_sinf(acc[mt][nt][r]);
      }
      *(f16x4*)&hb[wbase + (nt * 16 + lr) * 8] = hv;
    }
  }
  __syncthreads();
}

__global__ __launch_bounds__(THREADS, 2) void siren_kernel(
    const float* __restrict__ coords, const float* __restrict__ bff,
    const float* __restrict__ biasC, const float* __restrict__ b_out,
    const _Float16* __restrict__ wf, const _Float16* __restrict__ wh,
    const _Float16* __restrict__ wo, float* __restrict__ out) {
  extern __shared__ _Float16 hb[];  // chunk-major: [64 chunks][128 tok][8]
  const int tid = threadIdx.x;
  const int t0 = blockIdx.x * TOK;

  // Break 2-wave/SIMD lockstep (r10's best config).
  if ((tid >> 6) < 4) __builtin_amdgcn_s_setprio(1);

  // ---- Fourier features: chunks q*4+cb (sin), 16+q*4+cb (cos) ----
  {
    const int t = tid & 127;   // token (wave = 64 consecutive tokens)
    const int q = tid >> 7;    // feature octant: proj j in [q*32, q*32+32)
    const float c0 = coords[(t0 + t) * 3 + 0];
    const float c1 = coords[(t0 + t) * 3 + 1];
    const float c2 = coords[(t0 + t) * 3 + 2];
#pragma unroll
    for (int cb = 0; cb < 4; ++cb) {
      f16x8 sv, cv;
#pragma unroll
      for (int e = 0; e < 8; ++e) {
        const int j = q * 32 + cb * 8 + e;
        // r in revolutions, |r| <= 3*max|B_ff| ~ 114 << 256: no fract
        float r = fmaf(c0, bff[j], fmaf(c1, bff[128 + j], c2 * bff[256 + j]));
        sv[e] = (_Float16)__builtin_amdgcn_sinf(r);
        cv[e] = (_Float16)__builtin_amdgcn_cosf(r);
      }
      *(f16x8*)&hb[h_elem(q * 4 + cb, t)] = sv;        // lane-linear store
      *(f16x8*)&hb[h_elem(16 + q * 4 + cb, t)] = cv;
    }
  }
  __syncthreads();

  const int lane = tid & 63;
  const int lr = lane & 15;   // A: weight row / B: token / C: token col
  const int lg = lane >> 4;   // k-group for frags, row-group for C
  const int m0 = (tid >> 6) * 64;  // wave's 64-feature output slice

  sine_layer<256>(wf, biasC, hb, lane, lr, lg, m0);
#pragma unroll 1
  for (int l = 0; l < 5; ++l)
    sine_layer<512>(wh + l * (512 * 512), biasC + 512 + l * 512, hb, lane, lr,
                    lg, m0);

  // ---- final linear: out[t][0..2], 16 tokens per wave, 8 waves ----
  {
    const int wave = tid >> 6;
    f32x4 acc = {0.f, 0.f, 0.f, 0.f};
#pragma unroll
    for (int ks = 0; ks < 16; ++ks) {
      f16x8 a = *(const f16x8*)&wo[lr * 512 + ks * 32 + lg * 8];
      f16x8 b = *(const f16x8*)&hb[h_elem(ks * 4 + lg, wave * 16 + lr)];
      acc = __builtin_amdgcn_mfma_f32_16x16x32_f16(a, b, acc, 0, 0, 0);
    }
    if (lg == 0) {  // C rows 0..3 in lanes 0..15; out-feature = reg idx
      const int t = t0 + wave * 16 + lr;
      out[t * 3 + 0] = acc[0] + b_out[0];
      out[t * 3 + 1] = acc[1] + b_out[1];
      out[t * 3 + 2] = acc[2] + b_out[2];
    }
  }
}

extern "C" void kernel_launch(void* const* d_in, const int* in_sizes, int n_in,
                              void* d_out, int out_size, void* d_ws,
                              size_t ws_size, hipStream_t stream) {
  const float* coords = (const float*)d_in[0];
  const float* bff    = (const float*)d_in[1];
  const float* Wf     = (const float*)d_in[2];
  const float* bf     = (const float*)d_in[3];
  const float* Wh     = (const float*)d_in[4];
  const float* bh     = (const float*)d_in[5];
  const float* Wo     = (const float*)d_in[6];
  const float* bo     = (const float*)d_in[7];
  float* out = (float*)d_out;

  _Float16* w16 = (_Float16*)d_ws;
  float* biasC = (float*)(w16 + N3);  // 16B-aligned (N3*2 % 16 == 0)

  convert_weights<<<(N3 + NBIAS + 255) / 256, 256, 0, stream>>>(
      Wf, Wh, Wo, bf, bh, w16, biasC);

  const size_t lds_bytes = 64 * 128 * 8 * sizeof(_Float16);  // 131072
  siren_kernel<<<L_TOTAL / TOK, THREADS, lds_bytes, stream>>>(
      coords, bff, biasC, bo, w16, w16 + N1, w16 + N2, out);
}